// Round 22
// baseline (1749.681 us; speedup 1.0000x reference)
//
#include <hip/hip_runtime.h>

#define D_MODEL 1024
#define NGROUPS 8
#define SUB 8192
#define TOPK 32
#define BATCH 2048
#define NTOT (NGROUPS * SUB)   // 65536

typedef float v4f __attribute__((ext_vector_type(4)));
typedef _Float16 f16x8 __attribute__((ext_vector_type(8)));
typedef _Float16 f16x4 __attribute__((ext_vector_type(4)));
typedef float f32x4 __attribute__((ext_vector_type(4)));

__device__ __forceinline__ unsigned fkey(float f) {
    unsigned u = __float_as_uint(f);
    return (u & 0x80000000u) ? ~u : (u | 0x80000000u);  // monotonic
}
__device__ __forceinline__ float inv_fkey(unsigned key) {
    unsigned u = (key & 0x80000000u) ? (key & 0x7FFFFFFFu) : ~key;
    return __uint_as_float(u);
}

// ===== k0a: xh = f16(x) =====
__global__ __launch_bounds__(256) void cvt_x_h(
    const float* __restrict__ x, _Float16* __restrict__ xh)
{
    const size_t i = ((size_t)blockIdx.x * 256 + threadIdx.x) * 8;
    const v4f a = *(const v4f*)(x + i);
    const v4f b = *(const v4f*)(x + i + 4);
    f16x8 h;
#pragma unroll
    for (int j = 0; j < 4; ++j) { h[j] = (_Float16)a[j]; h[4 + j] = (_Float16)b[j]; }
    *(f16x8*)(xh + i) = h;
}

// ===== k0b: Wd_h = f16(W_dec) =====
__global__ __launch_bounds__(256) void cvt_wdec_h(
    const float* __restrict__ Wd, _Float16* __restrict__ Wh)
{
    const size_t i = ((size_t)blockIdx.x * 256 + threadIdx.x) * 8;
    const v4f a = *(const v4f*)(Wd + i);
    const v4f b = *(const v4f*)(Wd + i + 4);
    f16x8 h;
#pragma unroll
    for (int j = 0; j < 4; ++j) { h[j] = (_Float16)a[j]; h[4 + j] = (_Float16)b[j]; }
    *(f16x8*)(Wh + i) = h;
}

// ===== k0c: streaming pre-zero of each group region's SECOND half =====
__global__ __launch_bounds__(256) void prezero_acts(float* __restrict__ out_acts)
{
    float4* p4 = (float4*)out_acts;
    const int tid = threadIdx.x;
#pragma unroll
    for (int i = 0; i < 8; ++i) {
        const size_t flat = (size_t)blockIdx.x * 2048 + (size_t)i * 256 + tid;
        const size_t r = flat >> 10, o = flat & 1023;
        p4[r * 2048 + 1024 + o] = make_float4(0.f, 0.f, 0.f, 0.f);
    }
}

// ===== k1: W_enc [g][k][s] -> WT f32 [g][s][k] + WhT f16 [g][s][k] =====
__global__ __launch_bounds__(256) void transpose_wenc2(
    const float* __restrict__ W, float* __restrict__ WT, _Float16* __restrict__ WhT)
{
    __shared__ float t[32][33];
    const int g = blockIdx.z, kt = blockIdx.y, st = blockIdx.x;
    const int lx = threadIdx.x & 31, ly = threadIdx.x >> 5;
    const float* Wg = W + (size_t)g * D_MODEL * SUB;
    float* WTg = WT + (size_t)g * SUB * D_MODEL;
    _Float16* WhTg = WhT + (size_t)g * SUB * D_MODEL;
#pragma unroll
    for (int r = 0; r < 4; ++r)
        t[ly + 8 * r][lx] = Wg[(size_t)(kt * 32 + ly + 8 * r) * SUB + st * 32 + lx];
    __syncthreads();
#pragma unroll
    for (int r = 0; r < 4; ++r) {
        const float v = t[lx][ly + 8 * r];
        const size_t o = (size_t)(st * 32 + ly + 8 * r) * D_MODEL + kt * 32 + lx;
        WTg[o] = v;
        WhTg[o] = (_Float16)v;
    }
}

// ===== k2: f16 MFMA scores, L2-DIRECT (no LDS, no barriers) =====
// xh (4MB) + each WhT strip (256KB, XCD-swizzled) are L2-resident; MFMA
// fragments load straight from global. Per-lane k-order identical to the
// LDS version => scores bit-identical. No barriers => compiler pipelines
// loads across K-steps; LDS=0 so occupancy is VGPR-bound.
// Score element (row,g,col): sb + (row*NTOT + g*SUB)*scale + col.
__global__ __launch_bounds__(256) void mfma_scores_l2(
    const _Float16* __restrict__ xh, const _Float16* __restrict__ WhT,
    const float* __restrict__ b_enc, _Float16* __restrict__ sb, const int scale)
{
    const int tid = threadIdx.x;
    const int wblk = blockIdx.x;
    const int t = (wblk & 7) * 1024 + (wblk >> 3);   // bijective: 8192 = 8*1024
    const int mt = t & 15, nt = t >> 4;
    const int g = nt >> 6;
    const int sbase = (nt & 63) * 128;
    const int mbase = mt * 128;

    const int lane = tid & 63, w = tid >> 6;
    const int wm = w >> 1, wn = w & 1;
    const int l15 = lane & 15, grp = lane >> 4;

    const _Float16* Ab[4];
    const _Float16* Bb[4];
#pragma unroll
    for (int i = 0; i < 4; ++i)
        Ab[i] = xh + (size_t)(mbase + wm * 64 + i * 16 + l15) * D_MODEL + 8 * grp;
#pragma unroll
    for (int j = 0; j < 4; ++j)
        Bb[j] = WhT + ((size_t)g * SUB + sbase + wn * 64 + j * 16 + l15) * D_MODEL + 8 * grp;

    f32x4 acc[4][4];
#pragma unroll
    for (int i = 0; i < 4; ++i)
#pragma unroll
        for (int j = 0; j < 4; ++j) acc[i][j] = (f32x4){0.f, 0.f, 0.f, 0.f};

#pragma unroll 1
    for (int it = 0; it < 32; ++it) {
        const int k0 = it * 32;
        f16x8 af[4], bf[4];
#pragma unroll
        for (int i = 0; i < 4; ++i) af[i] = *(const f16x8*)(Ab[i] + k0);
#pragma unroll
        for (int j = 0; j < 4; ++j) bf[j] = *(const f16x8*)(Bb[j] + k0);
#pragma unroll
        for (int i = 0; i < 4; ++i)
#pragma unroll
            for (int j = 0; j < 4; ++j)
                acc[i][j] = __builtin_amdgcn_mfma_f32_16x16x32_f16(af[i], bf[j], acc[i][j], 0, 0, 0);
    }

    float bb[4];
#pragma unroll
    for (int j = 0; j < 4; ++j)
        bb[j] = b_enc[(size_t)g * SUB + sbase + wn * 64 + j * 16 + l15];
#pragma unroll
    for (int i = 0; i < 4; ++i) {
        const int row = mbase + wm * 64 + i * 16 + grp * 4;
#pragma unroll
        for (int j = 0; j < 4; ++j) {
            const int cols = sbase + wn * 64 + j * 16 + l15;
#pragma unroll
            for (int r = 0; r < 4; ++r) {
                _Float16* hg = sb + ((size_t)(row + r) * NTOT + (size_t)g * SUB) * (size_t)scale;
                hg[cols] = (_Float16)__fadd_rn(acc[i][j][r], bb[j]);
            }
        }
    }
}

// ===== k3: certain/band classification + band-only exact recompute =====
#define CCAP 128
#define BCAP 512

__global__ __launch_bounds__(256) void select_decode_u(
    const float* __restrict__ x, const float* __restrict__ WT,
    const float* __restrict__ b_enc, const _Float16* __restrict__ Wd_h,
    float* __restrict__ out_recon, float* __restrict__ out_acts,
    const _Float16* __restrict__ sb, const int scale, const int do_zero)
{
    __shared__ float xrow[1024];
    __shared__ unsigned hist[256], sscan[256], wsum[4];
    __shared__ unsigned sh_bin, sh_above, cert_cnt, band_cnt;
    __shared__ int   cert_idx[CCAP];
    __shared__ float cert_val[CCAP];
    __shared__ int   band_idx[BCAP];   // (g<<13)|sidx
    __shared__ float band_val[BCAP];
    __shared__ int   gcend[4], gbend[4];
    __shared__ int   sel_idx[TOPK];
    __shared__ float sel_val[TOPK];

    const int tid = threadIdx.x;
    const int lane = tid & 63;
    const int w = tid >> 6;
    const size_t b = blockIdx.x >> 1;
    const int h = blockIdx.x & 1;
    const int g0 = h * 4;

    *(float4*)&xrow[tid * 4] = *(const float4*)(x + b * D_MODEL + tid * 4);
    if (tid == 0) { cert_cnt = 0; band_cnt = 0; }
    float r0 = 0.f, r1 = 0.f, r2 = 0.f, r3 = 0.f;

    // ---- Phase 1a: per-group radix floor + classify ----
    for (int gi = 0; gi < 4; ++gi) {
        const int g = g0 + gi;
        const _Float16* hg = sb + (b * NTOT + (size_t)g * SUB) * (size_t)scale;
        float sc[32];
#pragma unroll
        for (int t = 0; t < 4; ++t) {
            const f16x8 hv = *(const f16x8*)(hg + (size_t)(tid + t * 256) * 8);
#pragma unroll
            for (int e = 0; e < 8; ++e) sc[t * 8 + e] = (float)hv[e];
        }

        hist[tid] = 0;
        __syncthreads();
#pragma unroll
        for (int j = 0; j < 32; ++j)
            atomicAdd(&hist[fkey(sc[j]) >> 24], 1u);
        __syncthreads();

        unsigned prefix = 0, kwant = TOPK;
#pragma unroll
        for (int r = 0; r < 2; ++r) {
            unsigned s = hist[tid];
#pragma unroll
            for (int off = 1; off < 64; off <<= 1) {
                const unsigned o = __shfl_down(s, off, 64);
                if (lane + off < 64) s += o;
            }
            if (lane == 0) wsum[w] = s;
            __syncthreads();
            unsigned add = 0;
            for (int w2 = w + 1; w2 < 4; ++w2) add += wsum[w2];
            s += add;
            sscan[tid] = s;
            __syncthreads();
            const unsigned snext = (tid < 255) ? sscan[tid + 1] : 0u;
            if (s >= kwant && snext < kwant) { sh_bin = (unsigned)tid; sh_above = snext; }
            __syncthreads();
            const int shift = 24 - 8 * r;
            prefix |= sh_bin << shift;
            kwant -= sh_above;
            __syncthreads();
            if (r == 0) {
                hist[tid] = 0;
                __syncthreads();
#pragma unroll
                for (int j = 0; j < 32; ++j) {
                    const unsigned key = fkey(sc[j]);
                    if ((key >> 24) == (prefix >> 24))
                        atomicAdd(&hist[(key >> 16) & 255u], 1u);
                }
                __syncthreads();
            }
        }
        const float F = inv_fkey(prefix);
        const unsigned supkey = fkey(F - 0.06f);
        const unsigned inkey  = fkey(F + 0.077f);

#pragma unroll
        for (int j = 0; j < 32; ++j) {
            const unsigned key = fkey(sc[j]);
            if (key >= supkey) {
                const int sidx = (tid + (j >> 3) * 256) * 8 + (j & 7);
                if (key > inkey) {
                    const unsigned slot = atomicAdd(&cert_cnt, 1u);
                    if (slot < CCAP) { cert_idx[slot] = (g << 13) | sidx; cert_val[slot] = fmaxf(sc[j], 0.f); }
                } else {
                    const unsigned slot = atomicAdd(&band_cnt, 1u);
                    if (slot < BCAP) band_idx[slot] = (g << 13) | sidx;
                }
            }
        }
        __syncthreads();
        if (tid == 0) { gcend[gi] = (int)min(cert_cnt, (unsigned)CCAP);
                        gbend[gi] = (int)min(band_cnt, (unsigned)BCAP); }
        __syncthreads();
    }

    // ---- Phase 1b (tier2 only): zero first halves (scores consumed) ----
    if (do_zero) {
        for (int gi = 0; gi < 4; ++gi) {
            float* rz = out_acts + b * NTOT + (size_t)(g0 + gi) * SUB;
#pragma unroll
            for (int t = 0; t < 4; ++t)
                *(float4*)(rz + (size_t)(tid + t * 256) * 4) = make_float4(0.f, 0.f, 0.f, 0.f);
        }
        __syncthreads();
    }

    // ---- Phase 2: exact BLAS-order recompute for BAND members only ----
    const int bcnt = gbend[3];
    for (int base = 0; base < bcnt; base += 256) {
        const int c = base + tid;
        if (c < bcnt) {
            const int id = band_idx[c];
            const int g = id >> 13, sidx = id & 8191;
            const float* col = WT + ((size_t)g * SUB + sidx) * D_MODEL;
            float a0 = 0.f, a1 = 0.f, a2 = 0.f;
#pragma unroll 4
            for (int q = 0; q < 64; ++q) {
                const float4 w0 = *(const float4*)(col + q * 4);
                const float4 w1 = *(const float4*)(col + 384 + q * 4);
                const float4 w2 = *(const float4*)(col + 768 + q * 4);
                a0 = fmaf(xrow[q * 4 + 0], w0.x, a0); a1 = fmaf(xrow[384 + q * 4 + 0], w1.x, a1); a2 = fmaf(xrow[768 + q * 4 + 0], w2.x, a2);
                a0 = fmaf(xrow[q * 4 + 1], w0.y, a0); a1 = fmaf(xrow[384 + q * 4 + 1], w1.y, a1); a2 = fmaf(xrow[768 + q * 4 + 1], w2.y, a2);
                a0 = fmaf(xrow[q * 4 + 2], w0.z, a0); a1 = fmaf(xrow[384 + q * 4 + 2], w1.z, a1); a2 = fmaf(xrow[768 + q * 4 + 2], w2.z, a2);
                a0 = fmaf(xrow[q * 4 + 3], w0.w, a0); a1 = fmaf(xrow[384 + q * 4 + 3], w1.w, a1); a2 = fmaf(xrow[768 + q * 4 + 3], w2.w, a2);
            }
#pragma unroll 4
            for (int q = 64; q < 96; ++q) {
                const float4 w0 = *(const float4*)(col + q * 4);
                const float4 w1 = *(const float4*)(col + 384 + q * 4);
                a0 = fmaf(xrow[q * 4 + 0], w0.x, a0); a1 = fmaf(xrow[384 + q * 4 + 0], w1.x, a1);
                a0 = fmaf(xrow[q * 4 + 1], w0.y, a0); a1 = fmaf(xrow[384 + q * 4 + 1], w1.y, a1);
                a0 = fmaf(xrow[q * 4 + 2], w0.z, a0); a1 = fmaf(xrow[384 + q * 4 + 2], w1.z, a1);
                a0 = fmaf(xrow[q * 4 + 3], w0.w, a0); a1 = fmaf(xrow[384 + q * 4 + 3], w1.w, a1);
            }
            band_val[c] = __fadd_rn(__fadd_rn(__fadd_rn(a0, a1), a2),
                                    b_enc[(size_t)g * SUB + sidx]);
        }
    }
    __syncthreads();

    // ---- Phase 3: assemble final 32 = cert + top-(32-n_in) of band; scatter; decode ----
    for (int gi = 0; gi < 4; ++gi) {
        const int g = g0 + gi;
        const int cb = (gi == 0) ? 0 : gcend[gi - 1];
        const int ce = gcend[gi];
        const int n_in = ce - cb;
        const int n_slots = TOPK - n_in;
        const int bb = (gi == 0) ? 0 : gbend[gi - 1];
        const int be = gbend[gi];

        if (tid < n_in) { sel_idx[tid] = cert_idx[cb + tid] & 8191; sel_val[tid] = cert_val[cb + tid]; }
        for (int t = bb + tid; t < be; t += 256) {
            const unsigned mykey = fkey(band_val[t]);
            const int mys = band_idx[t] & 8191;
            int rank = 0;
            for (int e = bb; e < be; ++e) {
                const unsigned ke = fkey(band_val[e]);
                if (ke > mykey || (ke == mykey && (band_idx[e] & 8191) < mys)) ++rank;
            }
            if (rank < n_slots) { sel_idx[n_in + rank] = mys; sel_val[n_in + rank] = fmaxf(band_val[t], 0.f); }
        }
        __syncthreads();

        float* rowg = out_acts + b * NTOT + (size_t)g * SUB;
        if (tid < TOPK) rowg[sel_idx[tid]] = sel_val[tid];

        const _Float16* Wgh = Wd_h + (size_t)g * SUB * D_MODEL + tid * 4;
#pragma unroll 8
        for (int j = 0; j < TOPK; ++j) {
            const float v = sel_val[j];
            const f16x4 wv = *(const f16x4*)(Wgh + (size_t)sel_idx[j] * D_MODEL);
            r0 = fmaf(v, (float)wv[0], r0); r1 = fmaf(v, (float)wv[1], r1);
            r2 = fmaf(v, (float)wv[2], r2); r3 = fmaf(v, (float)wv[3], r3);
        }
        __syncthreads();
    }
    float* rp = out_recon + b * D_MODEL + tid * 4;
    atomicAdd(rp + 0, r0); atomicAdd(rp + 1, r1);
    atomicAdd(rp + 2, r2); atomicAdd(rp + 3, r3);
}

// ===================== Tier 3: R5 exact fp32 fallback =====================
#define PIDX(s) ((s) + ((s) >> 5))
#define BM 64
#define BN 128
#define BK 16
#define LDSA 68
#define LDSB 132

__global__ __launch_bounds__(256) void fb_encode_gemm(
    const float* __restrict__ x, const float* __restrict__ W_enc,
    const float* __restrict__ b_enc, float* __restrict__ out_acts)
{
    __shared__ float As[BK * LDSA];
    __shared__ float Bs[BK * LDSB];
    const int tid = threadIdx.x;
    const int nt = blockIdx.x, mt = blockIdx.y;
    const int g = nt >> 6, sbase = (nt & 63) * BN, mbase = mt * BM;
    const float* Bp = W_enc + ((size_t)g * D_MODEL) * SUB + sbase;
    const float* Ap = x + (size_t)mbase * D_MODEL;
    const int a_m = tid >> 2, a_c = (tid & 3) * 4;
    const int b_k = tid >> 5, b_c = (tid & 31) * 4;
    const int tr = tid >> 4, tc = tid & 15;
    float tot[4][8], cur[4][8];
#pragma unroll
    for (int i = 0; i < 4; ++i)
#pragma unroll
        for (int j = 0; j < 8; ++j) { tot[i][j] = 0.f; cur[i][j] = 0.f; }
#pragma unroll 1
    for (int it = 0; it < 64; ++it) {
        const int k0 = it * BK;
        const v4f va = *(const v4f*)(Ap + (size_t)a_m * D_MODEL + k0 + a_c);
        const v4f vb0 = *(const v4f*)(Bp + (size_t)(k0 + b_k) * SUB + b_c);
        const v4f vb1 = *(const v4f*)(Bp + (size_t)(k0 + b_k + 8) * SUB + b_c);
#pragma unroll
        for (int j = 0; j < 4; ++j) As[(a_c + j) * LDSA + a_m] = va[j];
        *(v4f*)&Bs[b_k * LDSB + b_c] = vb0;
        *(v4f*)&Bs[(b_k + 8) * LDSB + b_c] = vb1;
        __syncthreads();
        if (it == 24 || it == 48) {
#pragma unroll
            for (int i = 0; i < 4; ++i)
#pragma unroll
                for (int j = 0; j < 8; ++j) { tot[i][j] = __fadd_rn(tot[i][j], cur[i][j]); cur[i][j] = 0.f; }
        }
#pragma unroll
        for (int kk = 0; kk < BK; ++kk) {
            float a[4], bb[8];
            *(v4f*)&a[0] = *(const v4f*)&As[kk * LDSA + tr * 4];
            *(v4f*)&bb[0] = *(const v4f*)&Bs[kk * LDSB + tc * 4];
            *(v4f*)&bb[4] = *(const v4f*)&Bs[kk * LDSB + tc * 4 + 64];
#pragma unroll
            for (int i = 0; i < 4; ++i)
#pragma unroll
                for (int j = 0; j < 8; ++j) cur[i][j] = fmaf(a[i], bb[j], cur[i][j]);
        }
        __syncthreads();
    }
#pragma unroll
    for (int i = 0; i < 4; ++i)
#pragma unroll
        for (int j = 0; j < 8; ++j) tot[i][j] = __fadd_rn(tot[i][j], cur[i][j]);
    const float* bias = b_enc + (size_t)g * SUB + sbase;
    const float4 bb0 = *(const float4*)(bias + tc * 4);
    const float4 bb1 = *(const float4*)(bias + tc * 4 + 64);
    float* outp = out_acts + (size_t)g * SUB + sbase;
#pragma unroll
    for (int i = 0; i < 4; ++i) {
        const size_t row = (size_t)(mbase + tr * 4 + i);
        const float4 o0 = make_float4(__fadd_rn(tot[i][0], bb0.x), __fadd_rn(tot[i][1], bb0.y),
                                      __fadd_rn(tot[i][2], bb0.z), __fadd_rn(tot[i][3], bb0.w));
        const float4 o1 = make_float4(__fadd_rn(tot[i][4], bb1.x), __fadd_rn(tot[i][5], bb1.y),
                                      __fadd_rn(tot[i][6], bb1.z), __fadd_rn(tot[i][7], bb1.w));
        *(float4*)(outp + row * NTOT + tc * 4) = o0;
        *(float4*)(outp + row * NTOT + tc * 4 + 64) = o1;
    }
}

__global__ __launch_bounds__(256) void fb_topk_decode(
    const float* __restrict__ W_dec, float* __restrict__ out_recon,
    float* __restrict__ out_acts)
{
    __shared__ float row[SUB + (SUB >> 5)];
    __shared__ unsigned hist[256], sscan[256], wsum[4], wsum2[4];
    __shared__ unsigned sh_bin, sh_above;
    __shared__ int sel_idx[TOPK];
    __shared__ float sel_val[TOPK];
    const int tid = threadIdx.x, lane = tid & 63, w = tid >> 6;
    const size_t b = blockIdx.x;
    float r0 = 0.f, r1 = 0.f, r2 = 0.f, r3 = 0.f;
    for (int g = 0; g < NGROUPS; ++g) {
        float* rowg = out_acts + b * NTOT + (size_t)g * SUB;
#pragma unroll
        for (int t = 0; t < 8; ++t) {
            const int i4 = tid + t * 256;
            const float4 v = *(const float4*)(rowg + (size_t)i4 * 4);
            const int s0 = i4 * 4;
            row[PIDX(s0) + 0] = v.x; row[PIDX(s0) + 1] = v.y;
            row[PIDX(s0) + 2] = v.z; row[PIDX(s0) + 3] = v.w;
        }
        __syncthreads();
        unsigned prefix = 0, kwant = TOPK;
#pragma unroll
        for (int r = 0; r < 4; ++r) {
            const int shift = 24 - 8 * r;
            hist[tid] = 0;
            __syncthreads();
            for (int j = 0; j < 32; ++j) {
                const unsigned key = fkey(row[tid * 33 + j]);
                const unsigned hi = (unsigned)(((unsigned long long)key) >> (shift + 8));
                const unsigned pi = (unsigned)(((unsigned long long)prefix) >> (shift + 8));
                if (hi == pi) atomicAdd(&hist[(key >> shift) & 255u], 1u);
            }
            __syncthreads();
            unsigned s = hist[tid];
#pragma unroll
            for (int off = 1; off < 64; off <<= 1) {
                const unsigned o = __shfl_down(s, off, 64);
                if (lane + off < 64) s += o;
            }
            if (lane == 0) wsum[w] = s;
            __syncthreads();
            unsigned add = 0;
            for (int w2 = w + 1; w2 < 4; ++w2) add += wsum[w2];
            s += add;
            sscan[tid] = s;
            __syncthreads();
            const unsigned snext = (tid < 255) ? sscan[tid + 1] : 0u;
            if (s >= kwant && snext < kwant) { sh_bin = (unsigned)tid; sh_above = snext; }
            __syncthreads();
            prefix |= sh_bin << shift;
            kwant -= sh_above;
            __syncthreads();
        }
        const unsigned T = prefix, n_take = kwant, cnt_gt_total = TOPK - n_take;
        unsigned loc_gt = 0, loc_eq = 0;
        for (int j = 0; j < 32; ++j) {
            const unsigned key = fkey(row[tid * 33 + j]);
            loc_gt += (key > T); loc_eq += (key == T);
        }
        const unsigned pack = loc_gt | (loc_eq << 16);
        unsigned sI = pack;
#pragma unroll
        for (int off = 1; off < 64; off <<= 1) {
            const unsigned o = __shfl_up(sI, off, 64);
            if (lane >= off) sI += o;
        }
        if (lane == 63) wsum2[w] = sI;
        __syncthreads();
        unsigned woff = 0;
        for (int w2 = 0; w2 < w; ++w2) woff += wsum2[w2];
        const unsigned excl = sI - pack + woff;
        unsigned run_gt = excl & 0xFFFFu, run_eq = excl >> 16;
        for (int j = 0; j < 32; ++j) {
            const int sidx = tid * 32 + j;
            const float f = row[tid * 33 + j];
            const unsigned key = fkey(f);
            const float act = fmaxf(f, 0.f);
            if (key > T) { sel_idx[run_gt] = sidx; sel_val[run_gt] = act; ++run_gt; row[tid * 33 + j] = act; }
            else if (key == T) {
                if (run_eq < n_take) { sel_idx[cnt_gt_total + run_eq] = sidx; sel_val[cnt_gt_total + run_eq] = act; row[tid * 33 + j] = act; }
                else row[tid * 33 + j] = 0.f;
                ++run_eq;
            } else row[tid * 33 + j] = 0.f;
        }
        __syncthreads();
#pragma unroll
        for (int t = 0; t < 8; ++t) {
            const int i4 = tid + t * 256;
            const int s0 = i4 * 4;
            *(float4*)(rowg + (size_t)i4 * 4) =
                make_float4(row[PIDX(s0)], row[PIDX(s0) + 1], row[PIDX(s0) + 2], row[PIDX(s0) + 3]);
        }
        const float* Wg = W_dec + (size_t)g * SUB * D_MODEL + tid * 4;
#pragma unroll 8
        for (int j = 0; j < TOPK; ++j) {
            const float v = sel_val[j];
            const float4 wv = *(const float4*)(Wg + (size_t)sel_idx[j] * D_MODEL);
            r0 = fmaf(v, wv.x, r0); r1 = fmaf(v, wv.y, r1);
            r2 = fmaf(v, wv.z, r2); r3 = fmaf(v, wv.w, r3);
        }
        __syncthreads();
    }
    *(float4*)(out_recon + b * D_MODEL + tid * 4) = make_float4(r0, r1, r2, r3);
}

extern "C" void kernel_launch(void* const* d_in, const int* in_sizes, int n_in,
                              void* d_out, int out_size, void* d_ws, size_t ws_size,
                              hipStream_t stream) {
    const float* x     = (const float*)d_in[0];
    const float* W_enc = (const float*)d_in[1];
    const float* b_enc = (const float*)d_in[2];
    const float* W_dec = (const float*)d_in[3];

    float* out_recon = (float*)d_out;
    float* out_acts  = (float*)d_out + (size_t)BATCH * D_MODEL;

    const size_t WT_BYTES = (size_t)NGROUPS * SUB * D_MODEL * 4;   // 268 MB
    const size_t WH_BYTES = (size_t)NGROUPS * SUB * D_MODEL * 2;   // 134 MB
    const size_t WD_BYTES = (size_t)NGROUPS * SUB * D_MODEL * 2;   // 134 MB
    const size_t XH_BYTES = (size_t)BATCH * D_MODEL * 2;           // 4 MB

    if (ws_size >= WT_BYTES + WH_BYTES + WD_BYTES + XH_BYTES) {
        float* WT = (float*)d_ws;
        _Float16* WhT = (_Float16*)((char*)d_ws + WT_BYTES);
        _Float16* WdH = (_Float16*)((char*)d_ws + WT_BYTES + WH_BYTES);
        _Float16* xh  = (_Float16*)((char*)d_ws + WT_BYTES + WH_BYTES + WD_BYTES);
        hipMemsetAsync(out_recon, 0, (size_t)BATCH * D_MODEL * 4, stream);
        cvt_x_h<<<BATCH * D_MODEL / 2048, 256, 0, stream>>>(x, xh);
        cvt_wdec_h<<<NGROUPS * SUB * D_MODEL / 2048, 256, 0, stream>>>(W_dec, WdH);
        transpose_wenc2<<<dim3(SUB / 32, D_MODEL / 32, NGROUPS), 256, 0, stream>>>(W_enc, WT, WhT);
        prezero_acts<<<8192, 256, 0, stream>>>(out_acts);
        mfma_scores_l2<<<8192, 256, 0, stream>>>(xh, WhT, b_enc, (_Float16*)out_acts, 2);
        select_decode_u<<<BATCH * 2, 256, 0, stream>>>(x, WT, b_enc, WdH, out_recon, out_acts,
                                                      (const _Float16*)out_acts, 2, 1);
    } else {
        fb_encode_gemm<<<dim3(NTOT / BN, BATCH / BM), 256, 0, stream>>>(x, W_enc, b_enc, out_acts);
        fb_topk_decode<<<BATCH, 256, 0, stream>>>(W_dec, out_recon, out_acts);
    }
}

// Round 23
// 1250.336 us; speedup vs baseline: 1.3994x; 1.3994x over previous
//
#include <hip/hip_runtime.h>

#define D_MODEL 1024
#define NGROUPS 8
#define SUB 8192
#define TOPK 32
#define BATCH 2048
#define NTOT (NGROUPS * SUB)   // 65536

typedef float v4f __attribute__((ext_vector_type(4)));
typedef _Float16 f16x8 __attribute__((ext_vector_type(8)));
typedef _Float16 f16x4 __attribute__((ext_vector_type(4)));
typedef float f32x4 __attribute__((ext_vector_type(4)));

__device__ __forceinline__ unsigned fkey(float f) {
    unsigned u = __float_as_uint(f);
    return (u & 0x80000000u) ? ~u : (u | 0x80000000u);  // monotonic
}
__device__ __forceinline__ float inv_fkey(unsigned key) {
    unsigned u = (key & 0x80000000u) ? (key & 0x7FFFFFFFu) : ~key;
    return __uint_as_float(u);
}

// ===== k0a: xh = f16(x) =====
__global__ __launch_bounds__(256) void cvt_x_h(
    const float* __restrict__ x, _Float16* __restrict__ xh)
{
    const size_t i = ((size_t)blockIdx.x * 256 + threadIdx.x) * 8;
    const v4f a = *(const v4f*)(x + i);
    const v4f b = *(const v4f*)(x + i + 4);
    f16x8 h;
#pragma unroll
    for (int j = 0; j < 4; ++j) { h[j] = (_Float16)a[j]; h[4 + j] = (_Float16)b[j]; }
    *(f16x8*)(xh + i) = h;
}

// ===== k0b: Wd_h = f16(W_dec) =====
__global__ __launch_bounds__(256) void cvt_wdec_h(
    const float* __restrict__ Wd, _Float16* __restrict__ Wh)
{
    const size_t i = ((size_t)blockIdx.x * 256 + threadIdx.x) * 8;
    const v4f a = *(const v4f*)(Wd + i);
    const v4f b = *(const v4f*)(Wd + i + 4);
    f16x8 h;
#pragma unroll
    for (int j = 0; j < 4; ++j) { h[j] = (_Float16)a[j]; h[4 + j] = (_Float16)b[j]; }
    *(f16x8*)(Wh + i) = h;
}

// ===== k0c: streaming pre-zero of each group region's SECOND half =====
__global__ __launch_bounds__(256) void prezero_acts(float* __restrict__ out_acts)
{
    float4* p4 = (float4*)out_acts;
    const int tid = threadIdx.x;
#pragma unroll
    for (int i = 0; i < 8; ++i) {
        const size_t flat = (size_t)blockIdx.x * 2048 + (size_t)i * 256 + tid;
        const size_t r = flat >> 10, o = flat & 1023;
        p4[r * 2048 + 1024 + o] = make_float4(0.f, 0.f, 0.f, 0.f);
    }
}

// ===== k1: W_enc [g][k][s] -> WT f32 [g][s][k] + WhT f16 [g][s][k] =====
__global__ __launch_bounds__(256) void transpose_wenc2(
    const float* __restrict__ W, float* __restrict__ WT, _Float16* __restrict__ WhT)
{
    __shared__ float t[32][33];
    const int g = blockIdx.z, kt = blockIdx.y, st = blockIdx.x;
    const int lx = threadIdx.x & 31, ly = threadIdx.x >> 5;
    const float* Wg = W + (size_t)g * D_MODEL * SUB;
    float* WTg = WT + (size_t)g * SUB * D_MODEL;
    _Float16* WhTg = WhT + (size_t)g * SUB * D_MODEL;
#pragma unroll
    for (int r = 0; r < 4; ++r)
        t[ly + 8 * r][lx] = Wg[(size_t)(kt * 32 + ly + 8 * r) * SUB + st * 32 + lx];
    __syncthreads();
#pragma unroll
    for (int r = 0; r < 4; ++r) {
        const float v = t[lx][ly + 8 * r];
        const size_t o = (size_t)(st * 32 + ly + 8 * r) * D_MODEL + kt * 32 + lx;
        WTg[o] = v;
        WhTg[o] = (_Float16)v;
    }
}

// ===== k2: f16 MFMA scores — R20 LDS single-buffer (validated optimum) =====
// R22 lesson: L2-direct fragment loads = 64 requests/instr vs LDS broadcast;
// request-rate bound at 2.4x slower. R18: dbuf halves occupancy. This shape wins.
__global__ __launch_bounds__(256) void mfma_scores_h2(
    const _Float16* __restrict__ xh, const _Float16* __restrict__ WhT,
    const float* __restrict__ b_enc, float* __restrict__ out_acts)
{
    __shared__ _Float16 Ah[128 * 40];
    __shared__ _Float16 Bh[128 * 40];

    const int tid = threadIdx.x;
    const int wblk = blockIdx.x;
    const int t = (wblk & 7) * 1024 + (wblk >> 3);   // bijective: 8192 = 8*1024
    const int mt = t & 15, nt = t >> 4;
    const int g = nt >> 6;
    const int sbase = (nt & 63) * 128;
    const int mbase = mt * 128;

    const int lane = tid & 63, w = tid >> 6;
    const int wm = w >> 1, wn = w & 1;
    const int l15 = lane & 15, grp = lane >> 4;

    const int sr = tid >> 1, kh16 = (tid & 1) * 16;

    const _Float16* Agp = xh + (size_t)mbase * D_MODEL;
    const _Float16* Bgp = WhT + ((size_t)g * SUB + sbase) * D_MODEL;

    f32x4 acc[4][4];
#pragma unroll
    for (int i = 0; i < 4; ++i)
#pragma unroll
        for (int j = 0; j < 4; ++j) acc[i][j] = (f32x4){0.f, 0.f, 0.f, 0.f};

#pragma unroll 1
    for (int it = 0; it < 32; ++it) {
        const int k0 = it * 32;
        const f16x8 a0 = *(const f16x8*)(Agp + (size_t)sr * D_MODEL + k0 + kh16);
        const f16x8 a1 = *(const f16x8*)(Agp + (size_t)sr * D_MODEL + k0 + kh16 + 8);
        const f16x8 b0 = *(const f16x8*)(Bgp + (size_t)sr * D_MODEL + k0 + kh16);
        const f16x8 b1 = *(const f16x8*)(Bgp + (size_t)sr * D_MODEL + k0 + kh16 + 8);

        *(f16x8*)&Ah[sr * 40 + kh16]     = a0;
        *(f16x8*)&Ah[sr * 40 + kh16 + 8] = a1;
        *(f16x8*)&Bh[sr * 40 + kh16]     = b0;
        *(f16x8*)&Bh[sr * 40 + kh16 + 8] = b1;
        __syncthreads();

        f16x8 af[4], bf[4];
#pragma unroll
        for (int i = 0; i < 4; ++i)
            af[i] = *(const f16x8*)&Ah[(wm * 64 + i * 16 + l15) * 40 + 8 * grp];
#pragma unroll
        for (int j = 0; j < 4; ++j)
            bf[j] = *(const f16x8*)&Bh[(wn * 64 + j * 16 + l15) * 40 + 8 * grp];
#pragma unroll
        for (int i = 0; i < 4; ++i)
#pragma unroll
            for (int j = 0; j < 4; ++j)
                acc[i][j] = __builtin_amdgcn_mfma_f32_16x16x32_f16(af[i], bf[j], acc[i][j], 0, 0, 0);
        __syncthreads();
    }

    float bb[4];
#pragma unroll
    for (int j = 0; j < 4; ++j)
        bb[j] = b_enc[(size_t)g * SUB + sbase + wn * 64 + j * 16 + l15];
#pragma unroll
    for (int i = 0; i < 4; ++i) {
        const int row = mbase + wm * 64 + i * 16 + grp * 4;
#pragma unroll
        for (int j = 0; j < 4; ++j) {
            const int cols = sbase + wn * 64 + j * 16 + l15;
#pragma unroll
            for (int r = 0; r < 4; ++r) {
                _Float16* hg = (_Float16*)(out_acts + (size_t)(row + r) * NTOT + (size_t)g * SUB);
                hg[cols] = (_Float16)__fadd_rn(acc[i][j][r], bb[j]);
            }
        }
    }
}

// ===== k3: certain/band classification + band-only exact recompute =====
#define CCAP 128
#define BCAP 512

__global__ __launch_bounds__(256) void select_decode_h4(
    const float* __restrict__ x, const float* __restrict__ WT,
    const float* __restrict__ b_enc, const _Float16* __restrict__ Wd_h,
    float* __restrict__ out_recon, float* __restrict__ out_acts)
{
    __shared__ float xrow[1024];
    __shared__ unsigned hist[256], sscan[256], wsum[4];
    __shared__ unsigned sh_bin, sh_above, cert_cnt, band_cnt;
    __shared__ int   cert_idx[CCAP];
    __shared__ float cert_val[CCAP];
    __shared__ int   band_idx[BCAP];   // (g<<13)|sidx
    __shared__ float band_val[BCAP];
    __shared__ int   gcend[4], gbend[4];
    __shared__ int   sel_idx[TOPK];
    __shared__ float sel_val[TOPK];

    const int tid = threadIdx.x;
    const int lane = tid & 63;
    const int w = tid >> 6;
    const size_t b = blockIdx.x >> 1;
    const int h = blockIdx.x & 1;
    const int g0 = h * 4;

    *(float4*)&xrow[tid * 4] = *(const float4*)(x + b * D_MODEL + tid * 4);
    if (tid == 0) { cert_cnt = 0; band_cnt = 0; }
    float r0 = 0.f, r1 = 0.f, r2 = 0.f, r3 = 0.f;

    // ---- Phase 1a: per-group radix floor + classify ----
    for (int gi = 0; gi < 4; ++gi) {
        const int g = g0 + gi;
        const _Float16* hg = (const _Float16*)(out_acts + b * NTOT + (size_t)g * SUB);
        float sc[32];
#pragma unroll
        for (int t = 0; t < 4; ++t) {
            const f16x8 hv = *(const f16x8*)(hg + (size_t)(tid + t * 256) * 8);
#pragma unroll
            for (int e = 0; e < 8; ++e) sc[t * 8 + e] = (float)hv[e];
        }

        hist[tid] = 0;
        __syncthreads();
#pragma unroll
        for (int j = 0; j < 32; ++j)
            atomicAdd(&hist[fkey(sc[j]) >> 24], 1u);
        __syncthreads();

        unsigned prefix = 0, kwant = TOPK;
#pragma unroll
        for (int r = 0; r < 2; ++r) {
            unsigned s = hist[tid];
#pragma unroll
            for (int off = 1; off < 64; off <<= 1) {
                const unsigned o = __shfl_down(s, off, 64);
                if (lane + off < 64) s += o;
            }
            if (lane == 0) wsum[w] = s;
            __syncthreads();
            unsigned add = 0;
            for (int w2 = w + 1; w2 < 4; ++w2) add += wsum[w2];
            s += add;
            sscan[tid] = s;
            __syncthreads();
            const unsigned snext = (tid < 255) ? sscan[tid + 1] : 0u;
            if (s >= kwant && snext < kwant) { sh_bin = (unsigned)tid; sh_above = snext; }
            __syncthreads();
            const int shift = 24 - 8 * r;
            prefix |= sh_bin << shift;
            kwant -= sh_above;
            __syncthreads();
            if (r == 0) {
                hist[tid] = 0;
                __syncthreads();
#pragma unroll
                for (int j = 0; j < 32; ++j) {
                    const unsigned key = fkey(sc[j]);
                    if ((key >> 24) == (prefix >> 24))
                        atomicAdd(&hist[(key >> 16) & 255u], 1u);
                }
                __syncthreads();
            }
        }
        const float F = inv_fkey(prefix);
        const unsigned supkey = fkey(F - 0.06f);
        const unsigned inkey  = fkey(F + 0.077f);

#pragma unroll
        for (int j = 0; j < 32; ++j) {
            const unsigned key = fkey(sc[j]);
            if (key >= supkey) {
                const int sidx = (tid + (j >> 3) * 256) * 8 + (j & 7);
                if (key > inkey) {
                    const unsigned slot = atomicAdd(&cert_cnt, 1u);
                    if (slot < CCAP) { cert_idx[slot] = (g << 13) | sidx; cert_val[slot] = fmaxf(sc[j], 0.f); }
                } else {
                    const unsigned slot = atomicAdd(&band_cnt, 1u);
                    if (slot < BCAP) band_idx[slot] = (g << 13) | sidx;
                }
            }
        }
        __syncthreads();
        if (tid == 0) { gcend[gi] = (int)min(cert_cnt, (unsigned)CCAP);
                        gbend[gi] = (int)min(band_cnt, (unsigned)BCAP); }
        __syncthreads();
    }

    // ---- Phase 1b: zero FIRST half of each group region (second half pre-zeroed) ----
    for (int gi = 0; gi < 4; ++gi) {
        float* rz = out_acts + b * NTOT + (size_t)(g0 + gi) * SUB;
#pragma unroll
        for (int t = 0; t < 4; ++t)
            *(float4*)(rz + (size_t)(tid + t * 256) * 4) = make_float4(0.f, 0.f, 0.f, 0.f);
    }
    __syncthreads();

    // ---- Phase 2: exact BLAS-order recompute for BAND members only ----
    const int bcnt = gbend[3];
    for (int base = 0; base < bcnt; base += 256) {
        const int c = base + tid;
        if (c < bcnt) {
            const int id = band_idx[c];
            const int g = id >> 13, sidx = id & 8191;
            const float* col = WT + ((size_t)g * SUB + sidx) * D_MODEL;
            float a0 = 0.f, a1 = 0.f, a2 = 0.f;
#pragma unroll 4
            for (int q = 0; q < 64; ++q) {
                const float4 w0 = *(const float4*)(col + q * 4);
                const float4 w1 = *(const float4*)(col + 384 + q * 4);
                const float4 w2 = *(const float4*)(col + 768 + q * 4);
                a0 = fmaf(xrow[q * 4 + 0], w0.x, a0); a1 = fmaf(xrow[384 + q * 4 + 0], w1.x, a1); a2 = fmaf(xrow[768 + q * 4 + 0], w2.x, a2);
                a0 = fmaf(xrow[q * 4 + 1], w0.y, a0); a1 = fmaf(xrow[384 + q * 4 + 1], w1.y, a1); a2 = fmaf(xrow[768 + q * 4 + 1], w2.y, a2);
                a0 = fmaf(xrow[q * 4 + 2], w0.z, a0); a1 = fmaf(xrow[384 + q * 4 + 2], w1.z, a1); a2 = fmaf(xrow[768 + q * 4 + 2], w2.z, a2);
                a0 = fmaf(xrow[q * 4 + 3], w0.w, a0); a1 = fmaf(xrow[384 + q * 4 + 3], w1.w, a1); a2 = fmaf(xrow[768 + q * 4 + 3], w2.w, a2);
            }
#pragma unroll 4
            for (int q = 64; q < 96; ++q) {
                const float4 w0 = *(const float4*)(col + q * 4);
                const float4 w1 = *(const float4*)(col + 384 + q * 4);
                a0 = fmaf(xrow[q * 4 + 0], w0.x, a0); a1 = fmaf(xrow[384 + q * 4 + 0], w1.x, a1);
                a0 = fmaf(xrow[q * 4 + 1], w0.y, a0); a1 = fmaf(xrow[384 + q * 4 + 1], w1.y, a1);
                a0 = fmaf(xrow[q * 4 + 2], w0.z, a0); a1 = fmaf(xrow[384 + q * 4 + 2], w1.z, a1);
                a0 = fmaf(xrow[q * 4 + 3], w0.w, a0); a1 = fmaf(xrow[384 + q * 4 + 3], w1.w, a1);
            }
            band_val[c] = __fadd_rn(__fadd_rn(__fadd_rn(a0, a1), a2),
                                    b_enc[(size_t)g * SUB + sidx]);
        }
    }
    __syncthreads();

    // ---- Phase 3: assemble final 32 = cert + top-(32-n_in) of band; scatter; decode ----
    for (int gi = 0; gi < 4; ++gi) {
        const int g = g0 + gi;
        const int cb = (gi == 0) ? 0 : gcend[gi - 1];
        const int ce = gcend[gi];
        const int n_in = ce - cb;
        const int n_slots = TOPK - n_in;
        const int bb = (gi == 0) ? 0 : gbend[gi - 1];
        const int be = gbend[gi];

        if (tid < n_in) { sel_idx[tid] = cert_idx[cb + tid] & 8191; sel_val[tid] = cert_val[cb + tid]; }
        for (int t = bb + tid; t < be; t += 256) {
            const unsigned mykey = fkey(band_val[t]);
            const int mys = band_idx[t] & 8191;
            int rank = 0;
            for (int e = bb; e < be; ++e) {
                const unsigned ke = fkey(band_val[e]);
                if (ke > mykey || (ke == mykey && (band_idx[e] & 8191) < mys)) ++rank;
            }
            if (rank < n_slots) { sel_idx[n_in + rank] = mys; sel_val[n_in + rank] = fmaxf(band_val[t], 0.f); }
        }
        __syncthreads();

        float* rowg = out_acts + b * NTOT + (size_t)g * SUB;
        if (tid < TOPK) rowg[sel_idx[tid]] = sel_val[tid];

        const _Float16* Wgh = Wd_h + (size_t)g * SUB * D_MODEL + tid * 4;
#pragma unroll 8
        for (int j = 0; j < TOPK; ++j) {
            const float v = sel_val[j];
            const f16x4 wv = *(const f16x4*)(Wgh + (size_t)sel_idx[j] * D_MODEL);
            r0 = fmaf(v, (float)wv[0], r0); r1 = fmaf(v, (float)wv[1], r1);
            r2 = fmaf(v, (float)wv[2], r2); r3 = fmaf(v, (float)wv[3], r3);
        }
        __syncthreads();
    }
    float* rp = out_recon + b * D_MODEL + tid * 4;
    atomicAdd(rp + 0, r0); atomicAdd(rp + 1, r1);
    atomicAdd(rp + 2, r2); atomicAdd(rp + 3, r3);
}

// ===================== Tier 3: R5 exact fp32 fallback =====================
#define PIDX(s) ((s) + ((s) >> 5))
#define BM 64
#define BN 128
#define BK 16
#define LDSA 68
#define LDSB 132

__global__ __launch_bounds__(256) void fb_encode_gemm(
    const float* __restrict__ x, const float* __restrict__ W_enc,
    const float* __restrict__ b_enc, float* __restrict__ out_acts)
{
    __shared__ float As[BK * LDSA];
    __shared__ float Bs[BK * LDSB];
    const int tid = threadIdx.x;
    const int nt = blockIdx.x, mt = blockIdx.y;
    const int g = nt >> 6, sbase = (nt & 63) * BN, mbase = mt * BM;
    const float* Bp = W_enc + ((size_t)g * D_MODEL) * SUB + sbase;
    const float* Ap = x + (size_t)mbase * D_MODEL;
    const int a_m = tid >> 2, a_c = (tid & 3) * 4;
    const int b_k = tid >> 5, b_c = (tid & 31) * 4;
    const int tr = tid >> 4, tc = tid & 15;
    float tot[4][8], cur[4][8];
#pragma unroll
    for (int i = 0; i < 4; ++i)
#pragma unroll
        for (int j = 0; j < 8; ++j) { tot[i][j] = 0.f; cur[i][j] = 0.f; }
#pragma unroll 1
    for (int it = 0; it < 64; ++it) {
        const int k0 = it * BK;
        const v4f va = *(const v4f*)(Ap + (size_t)a_m * D_MODEL + k0 + a_c);
        const v4f vb0 = *(const v4f*)(Bp + (size_t)(k0 + b_k) * SUB + b_c);
        const v4f vb1 = *(const v4f*)(Bp + (size_t)(k0 + b_k + 8) * SUB + b_c);
#pragma unroll
        for (int j = 0; j < 4; ++j) As[(a_c + j) * LDSA + a_m] = va[j];
        *(v4f*)&Bs[b_k * LDSB + b_c] = vb0;
        *(v4f*)&Bs[(b_k + 8) * LDSB + b_c] = vb1;
        __syncthreads();
        if (it == 24 || it == 48) {
#pragma unroll
            for (int i = 0; i < 4; ++i)
#pragma unroll
                for (int j = 0; j < 8; ++j) { tot[i][j] = __fadd_rn(tot[i][j], cur[i][j]); cur[i][j] = 0.f; }
        }
#pragma unroll
        for (int kk = 0; kk < BK; ++kk) {
            float a[4], bb[8];
            *(v4f*)&a[0] = *(const v4f*)&As[kk * LDSA + tr * 4];
            *(v4f*)&bb[0] = *(const v4f*)&Bs[kk * LDSB + tc * 4];
            *(v4f*)&bb[4] = *(const v4f*)&Bs[kk * LDSB + tc * 4 + 64];
#pragma unroll
            for (int i = 0; i < 4; ++i)
#pragma unroll
                for (int j = 0; j < 8; ++j) cur[i][j] = fmaf(a[i], bb[j], cur[i][j]);
        }
        __syncthreads();
    }
#pragma unroll
    for (int i = 0; i < 4; ++i)
#pragma unroll
        for (int j = 0; j < 8; ++j) tot[i][j] = __fadd_rn(tot[i][j], cur[i][j]);
    const float* bias = b_enc + (size_t)g * SUB + sbase;
    const float4 bb0 = *(const float4*)(bias + tc * 4);
    const float4 bb1 = *(const float4*)(bias + tc * 4 + 64);
    float* outp = out_acts + (size_t)g * SUB + sbase;
#pragma unroll
    for (int i = 0; i < 4; ++i) {
        const size_t row = (size_t)(mbase + tr * 4 + i);
        const float4 o0 = make_float4(__fadd_rn(tot[i][0], bb0.x), __fadd_rn(tot[i][1], bb0.y),
                                      __fadd_rn(tot[i][2], bb0.z), __fadd_rn(tot[i][3], bb0.w));
        const float4 o1 = make_float4(__fadd_rn(tot[i][4], bb1.x), __fadd_rn(tot[i][5], bb1.y),
                                      __fadd_rn(tot[i][6], bb1.z), __fadd_rn(tot[i][7], bb1.w));
        *(float4*)(outp + row * NTOT + tc * 4) = o0;
        *(float4*)(outp + row * NTOT + tc * 4 + 64) = o1;
    }
}

__global__ __launch_bounds__(256) void fb_topk_decode(
    const float* __restrict__ W_dec, float* __restrict__ out_recon,
    float* __restrict__ out_acts)
{
    __shared__ float row[SUB + (SUB >> 5)];
    __shared__ unsigned hist[256], sscan[256], wsum[4], wsum2[4];
    __shared__ unsigned sh_bin, sh_above;
    __shared__ int sel_idx[TOPK];
    __shared__ float sel_val[TOPK];
    const int tid = threadIdx.x, lane = tid & 63, w = tid >> 6;
    const size_t b = blockIdx.x;
    float r0 = 0.f, r1 = 0.f, r2 = 0.f, r3 = 0.f;
    for (int g = 0; g < NGROUPS; ++g) {
        float* rowg = out_acts + b * NTOT + (size_t)g * SUB;
#pragma unroll
        for (int t = 0; t < 8; ++t) {
            const int i4 = tid + t * 256;
            const float4 v = *(const float4*)(rowg + (size_t)i4 * 4);
            const int s0 = i4 * 4;
            row[PIDX(s0) + 0] = v.x; row[PIDX(s0) + 1] = v.y;
            row[PIDX(s0) + 2] = v.z; row[PIDX(s0) + 3] = v.w;
        }
        __syncthreads();
        unsigned prefix = 0, kwant = TOPK;
#pragma unroll
        for (int r = 0; r < 4; ++r) {
            const int shift = 24 - 8 * r;
            hist[tid] = 0;
            __syncthreads();
            for (int j = 0; j < 32; ++j) {
                const unsigned key = fkey(row[tid * 33 + j]);
                const unsigned hi = (unsigned)(((unsigned long long)key) >> (shift + 8));
                const unsigned pi = (unsigned)(((unsigned long long)prefix) >> (shift + 8));
                if (hi == pi) atomicAdd(&hist[(key >> shift) & 255u], 1u);
            }
            __syncthreads();
            unsigned s = hist[tid];
#pragma unroll
            for (int off = 1; off < 64; off <<= 1) {
                const unsigned o = __shfl_down(s, off, 64);
                if (lane + off < 64) s += o;
            }
            if (lane == 0) wsum[w] = s;
            __syncthreads();
            unsigned add = 0;
            for (int w2 = w + 1; w2 < 4; ++w2) add += wsum[w2];
            s += add;
            sscan[tid] = s;
            __syncthreads();
            const unsigned snext = (tid < 255) ? sscan[tid + 1] : 0u;
            if (s >= kwant && snext < kwant) { sh_bin = (unsigned)tid; sh_above = snext; }
            __syncthreads();
            prefix |= sh_bin << shift;
            kwant -= sh_above;
            __syncthreads();
        }
        const unsigned T = prefix, n_take = kwant, cnt_gt_total = TOPK - n_take;
        unsigned loc_gt = 0, loc_eq = 0;
        for (int j = 0; j < 32; ++j) {
            const unsigned key = fkey(row[tid * 33 + j]);
            loc_gt += (key > T); loc_eq += (key == T);
        }
        const unsigned pack = loc_gt | (loc_eq << 16);
        unsigned sI = pack;
#pragma unroll
        for (int off = 1; off < 64; off <<= 1) {
            const unsigned o = __shfl_up(sI, off, 64);
            if (lane >= off) sI += o;
        }
        if (lane == 63) wsum2[w] = sI;
        __syncthreads();
        unsigned woff = 0;
        for (int w2 = 0; w2 < w; ++w2) woff += wsum2[w2];
        const unsigned excl = sI - pack + woff;
        unsigned run_gt = excl & 0xFFFFu, run_eq = excl >> 16;
        for (int j = 0; j < 32; ++j) {
            const int sidx = tid * 32 + j;
            const float f = row[tid * 33 + j];
            const unsigned key = fkey(f);
            const float act = fmaxf(f, 0.f);
            if (key > T) { sel_idx[run_gt] = sidx; sel_val[run_gt] = act; ++run_gt; row[tid * 33 + j] = act; }
            else if (key == T) {
                if (run_eq < n_take) { sel_idx[cnt_gt_total + run_eq] = sidx; sel_val[cnt_gt_total + run_eq] = act; row[tid * 33 + j] = act; }
                else row[tid * 33 + j] = 0.f;
                ++run_eq;
            } else row[tid * 33 + j] = 0.f;
        }
        __syncthreads();
#pragma unroll
        for (int t = 0; t < 8; ++t) {
            const int i4 = tid + t * 256;
            const int s0 = i4 * 4;
            *(float4*)(rowg + (size_t)i4 * 4) =
                make_float4(row[PIDX(s0)], row[PIDX(s0) + 1], row[PIDX(s0) + 2], row[PIDX(s0) + 3]);
        }
        const float* Wg = W_dec + (size_t)g * SUB * D_MODEL + tid * 4;
#pragma unroll 8
        for (int j = 0; j < TOPK; ++j) {
            const float v = sel_val[j];
            const float4 wv = *(const float4*)(Wg + (size_t)sel_idx[j] * D_MODEL);
            r0 = fmaf(v, wv.x, r0); r1 = fmaf(v, wv.y, r1);
            r2 = fmaf(v, wv.z, r2); r3 = fmaf(v, wv.w, r3);
        }
        __syncthreads();
    }
    *(float4*)(out_recon + b * D_MODEL + tid * 4) = make_float4(r0, r1, r2, r3);
}

extern "C" void kernel_launch(void* const* d_in, const int* in_sizes, int n_in,
                              void* d_out, int out_size, void* d_ws, size_t ws_size,
                              hipStream_t stream) {
    const float* x     = (const float*)d_in[0];
    const float* W_enc = (const float*)d_in[1];
    const float* b_enc = (const float*)d_in[2];
    const float* W_dec = (const float*)d_in[3];

    float* out_recon = (float*)d_out;
    float* out_acts  = (float*)d_out + (size_t)BATCH * D_MODEL;

    const size_t WT_BYTES = (size_t)NGROUPS * SUB * D_MODEL * 4;   // 268 MB
    const size_t WH_BYTES = (size_t)NGROUPS * SUB * D_MODEL * 2;   // 134 MB
    const size_t WD_BYTES = (size_t)NGROUPS * SUB * D_MODEL * 2;   // 134 MB
    const size_t XH_BYTES = (size_t)BATCH * D_MODEL * 2;           // 4 MB

    if (ws_size >= WT_BYTES + WH_BYTES + WD_BYTES + XH_BYTES) {
        float* WT = (float*)d_ws;
        _Float16* WhT = (_Float16*)((char*)d_ws + WT_BYTES);
        _Float16* WdH = (_Float16*)((char*)d_ws + WT_BYTES + WH_BYTES);
        _Float16* xh  = (_Float16*)((char*)d_ws + WT_BYTES + WH_BYTES + WD_BYTES);
        hipMemsetAsync(out_recon, 0, (size_t)BATCH * D_MODEL * 4, stream);
        cvt_x_h<<<BATCH * D_MODEL / 2048, 256, 0, stream>>>(x, xh);
        cvt_wdec_h<<<NGROUPS * SUB * D_MODEL / 2048, 256, 0, stream>>>(W_dec, WdH);
        transpose_wenc2<<<dim3(SUB / 32, D_MODEL / 32, NGROUPS), 256, 0, stream>>>(W_enc, WT, WhT);
        prezero_acts<<<8192, 256, 0, stream>>>(out_acts);
        mfma_scores_h2<<<8192, 256, 0, stream>>>(xh, WhT, b_enc, out_acts);
        select_decode_h4<<<BATCH * 2, 256, 0, stream>>>(x, WT, b_enc, WdH, out_recon, out_acts);
    } else {
        fb_encode_gemm<<<dim3(NTOT / BN, BATCH / BM), 256, 0, stream>>>(x, W_enc, b_enc, out_acts);
        fb_topk_decode<<<BATCH, 256, 0, stream>>>(W_dec, out_recon, out_acts);
    }
}